// Round 7
// baseline (183.415 us; speedup 1.0000x reference)
//
#include <hip/hip_runtime.h>
#include <stdint.h>

#define NINPUTS   1024
#define NOUTPUTS  1024
#define NMID      31          // middle layers
#define NN        4096        // neurons per layer
#define W         65536       // bit-array width
#define CHUNK     128         // columns per chunk (512-B rows: min clean HBM granule)
#define WPN       4           // u32 words per row (CHUNK/32)
#define NCHUNKS   (W / CHUNK) // 512
#define GRID      256         // 1 WG per CU
#define CPW       (NCHUNKS / GRID)   // 2 chunks per WG, pipelined
#define THREADS   1024
#define NPAIRS    16          // fused layer-pairs (L0,L1)..(L30,L31); L32 single
#define TBL_BYTES ((size_t)NPAIRS * NN * 16)

// ---------------------------------------------------------------------------
// Prep kernel: build fused 2-layer tables, CLASS-BALANCED processing order.
// Pair F computes layer 2F+1 from layer 2F's input state:
//   r = (((s[a1]&s[b1])^m1) & ((s[a2]&s[b2])^m2)) ^ m3
// Entry (uint4 e): e.x = a1 | b1<<16 ; e.y = a2 | b2<<16 ;
//                  e.z = dst | m1<<29 | m2<<30 | m3<<31 ; e.w = 0.
// (all offsets are LDS byte offsets, <= 65520, fit 16 bits)
// Neurons are counting-sorted by key (clsA1,clsB1,clsA2,clsB2), cls=(off>>4)&7,
// then DEALT so one wave-op (64 consecutive table slots) gets every-64th sorted
// entry -> each op sees a near-uniform slice of bank-class space -> gather
// reads approach the 8-cyc LDS floor instead of random-multinomial conflicts.
// Within-bin order from LDS atomics is nondeterministic, but the computed
// OUTPUT is order-invariant (each neuron writes its own slot).
// One block per F (16 blocks x 1024 threads).
// ---------------------------------------------------------------------------
__global__ __launch_bounds__(1024)
void build_sorted_tbl_kernel(const int*      __restrict__ idx_first,
                             const uint32_t* __restrict__ mask_first,
                             const int*      __restrict__ idx_mid,
                             const uint32_t* __restrict__ mask_mid,
                             uint4*          __restrict__ tbl)
{
    __shared__ uint32_t hist[4096];
    __shared__ uint32_t wsum[1024];
    const int F = blockIdx.x;
    const int t = threadIdx.x;

    const int*      i1;
    const uint32_t* m1;
    if (F == 0) { i1 = idx_first; m1 = mask_first; }
    else        { i1 = idx_mid + (size_t)(2 * F - 1) * NN * 2;
                  m1 = mask_mid + (size_t)(2 * F - 1) * NN; }
    const int*      i2 = idx_mid + (size_t)(2 * F) * NN * 2;
    const uint32_t* m2 = mask_mid + (size_t)(2 * F) * NN;

    #pragma unroll
    for (int k = 0; k < 4; ++k) hist[k * 1024 + t] = 0;
    __syncthreads();

    uint4    ent[4];
    uint32_t key[4];
    #pragma unroll
    for (int k = 0; k < 4; ++k) {
        const int n = k * 1024 + t;
        const int j  = i2[2 * n];
        const int kk = i2[2 * n + 1];
        const uint32_t a1 = (uint32_t)i1[2 * j]      * 16u;
        const uint32_t b1 = (uint32_t)i1[2 * j + 1]  * 16u;
        const uint32_t a2 = (uint32_t)i1[2 * kk]     * 16u;
        const uint32_t b2 = (uint32_t)i1[2 * kk + 1] * 16u;
        uint32_t mz = (uint32_t)(n * 16);
        if (m1[j])  mz |= 1u << 29;
        if (m1[kk]) mz |= 1u << 30;
        if (m2[n])  mz |= 1u << 31;
        ent[k].x = a1 | (b1 << 16);
        ent[k].y = a2 | (b2 << 16);
        ent[k].z = mz;
        ent[k].w = 0;
        key[k] = (((a1 >> 4) & 7u) << 9) | (((b1 >> 4) & 7u) << 6) |
                 (((a2 >> 4) & 7u) << 3) |  ((b2 >> 4) & 7u);
        atomicAdd(&hist[key[k]], 1u);
    }
    __syncthreads();

    // exclusive prefix sum over hist[4096]: thread t owns bins 4t..4t+3
    const uint32_t l0 = hist[4 * t], l1 = hist[4 * t + 1];
    const uint32_t l2 = hist[4 * t + 2], l3 = hist[4 * t + 3];
    const uint32_t lsum = l0 + l1 + l2 + l3;
    wsum[t] = lsum;
    __syncthreads();
    for (int off = 1; off < 1024; off <<= 1) {
        const uint32_t v = (t >= off) ? wsum[t - off] : 0u;
        __syncthreads();
        wsum[t] += v;
        __syncthreads();
    }
    const uint32_t excl = wsum[t] - lsum;
    hist[4 * t]     = excl;
    hist[4 * t + 1] = excl + l0;
    hist[4 * t + 2] = excl + l0 + l1;
    hist[4 * t + 3] = excl + l0 + l1 + l2;
    __syncthreads();

    // scatter with every-64th dealing: sorted pos p -> op (p&63), lane (p>>6)
    #pragma unroll
    for (int k = 0; k < 4; ++k) {
        const uint32_t p  = atomicAdd(&hist[key[k]], 1u);
        const uint32_t op = p & 63u;
        const uint32_t idx = (op >> 4) * 1024u + (op & 15u) * 64u + (p >> 6);
        tbl[(size_t)F * NN + idx] = ent[k];
    }
}

// ---------------------------------------------------------------------------
// Main kernel: identical structure to R6 (17 rounds/chunk, pipelined
// pack/unpack, register table prefetch); gather decode matches the new
// entry packing, and the result is scatter-written via the table's dst.
// LDS 160 KiB: P (16K) | X (64K) | Y (64K) | R (16K).
// ---------------------------------------------------------------------------
__global__ __launch_bounds__(THREADS, 4)
void nand_fused_kernel(const uint32_t* __restrict__ in,         // [1024][W]
                       const uint4*    __restrict__ tbl,        // [16][NN]
                       const int*      __restrict__ idx_last,   // [NOUTPUTS][2]
                       const uint32_t* __restrict__ mask_last,  // [NOUTPUTS]
                       uint32_t*       __restrict__ out)        // [NOUTPUTS][W]
{
    __shared__ uint32_t lds[40960];          // 160 KiB exactly
    uint32_t* P = lds;                       // 1024 * 4 dwords (16 KB)
    uint32_t* X = lds + 4096;                // 4096 * 4 dwords (64 KB)
    uint32_t* Y = lds + 20480;               // 4096 * 4 dwords (64 KB)
    uint32_t* R = lds + 36864;               // 1024 * 4 dwords (16 KB)

    const int t      = threadIdx.x;
    const int l      = t & 63;
    const int wv     = t >> 6;               // wave 0..15
    const int lane32 = l & 31;
    const int half   = l >> 5;
    const int shift  = half ? 32 : 0;
    const int bcol   = blockIdx.x * (CPW * CHUNK);

    // ---------------- prologue: pack chunk 0 fully into P ----------------
    #pragma unroll 4
    for (int s = 0; s < 32; ++s) {
        const int r = s * 32 + wv * 2 + half;
        const uint4 v = *(const uint4*)(in + (size_t)r * W + bcol + lane32 * 4);
        const unsigned long long b0 = __ballot(v.x != 0u);
        const unsigned long long b1 = __ballot(v.y != 0u);
        const unsigned long long b2 = __ballot(v.z != 0u);
        const unsigned long long b3 = __ballot(v.w != 0u);
        if (lane32 == 0) {
            uint4 w;
            w.x = (uint32_t)(b0 >> shift);
            w.y = (uint32_t)(b1 >> shift);
            w.z = (uint32_t)(b2 >> shift);
            w.w = (uint32_t)(b3 >> shift);
            *(uint4*)&P[r * WPN] = w;
        }
    }
    __syncthreads();

    for (int i = 0; i < CPW; ++i) {
        const int c0n = bcol + (i + 1) * CHUNK;      // pack source cols
        const int c0p = bcol + (i - 1) * CHUNK;      // unpack dest cols
        const bool do_pack   = (i + 1 < CPW);
        const bool do_unpack = (i > 0);

        // cold-load round-0 table entries for this chunk
        uint4 tc[4], tn[4];
        #pragma unroll
        for (int k = 0; k < 4; ++k) tc[k] = tbl[k * THREADS + t];

        for (int F = 0; F <= 16; ++F) {
            // (a) issue next-chunk input loads (2 rows/thread -> 64 rows/WG)
            uint4 pv0 = {0,0,0,0}, pv1 = {0,0,0,0};
            int pr0 = 0, pr1 = 0;
            if (do_pack && F >= 1) {
                pr0 = (F - 1) * 64 + wv * 2 + half;
                pr1 = pr0 + 32;
                pv0 = *(const uint4*)(in + (size_t)pr0 * W + c0n + lane32 * 4);
                pv1 = *(const uint4*)(in + (size_t)pr1 * W + c0n + lane32 * 4);
            }
            // (a') prefetch next round's table entries
            if (F <= 14) {
                #pragma unroll
                for (int k = 0; k < 4; ++k)
                    tn[k] = tbl[(size_t)(F + 1) * NN + k * THREADS + t];
            }

            // (b) fused gather-NAND (pure LDS + VALU, tables in registers)
            if (F <= 15) {
                const uint32_t* src = (F == 0) ? P : ((F & 1) ? X : Y);
                uint32_t*       dst = (F & 1) ? Y : X;
                #pragma unroll
                for (int k = 0; k < 4; ++k) {
                    const uint4 e = tc[k];
                    const uint32_t a1 = e.x & 0xFFFFu, b1 = e.x >> 16;
                    const uint32_t a2 = e.y & 0xFFFFu, b2 = e.y >> 16;
                    const uint32_t d0 = e.z & 0xFFFFu;
                    const uint32_t xm1 = (uint32_t)((int32_t)(e.z << 2) >> 31);
                    const uint32_t xm2 = (uint32_t)((int32_t)(e.z << 1) >> 31);
                    const uint32_t xm3 = (uint32_t)((int32_t)e.z >> 31);
                    const uint4 a = *(const uint4*)((const char*)src + a1);
                    const uint4 b = *(const uint4*)((const char*)src + b1);
                    const uint4 c = *(const uint4*)((const char*)src + a2);
                    const uint4 d = *(const uint4*)((const char*)src + b2);
                    uint4 r;
                    r.x = (((a.x & b.x) ^ xm1) & ((c.x & d.x) ^ xm2)) ^ xm3;
                    r.y = (((a.y & b.y) ^ xm1) & ((c.y & d.y) ^ xm2)) ^ xm3;
                    r.z = (((a.z & b.z) ^ xm1) & ((c.z & d.z) ^ xm2)) ^ xm3;
                    r.w = (((a.w & b.w) ^ xm1) & ((c.w & d.w) ^ xm2)) ^ xm3;
                    *(uint4*)((char*)dst + d0) = r;
                }
            } else {                                 // F == 16: last layer Y -> R
                const int n = t;
                const int2 ij = ((const int2*)idx_last)[n];
                const uint32_t xm = mask_last[n] ? 0xFFFFFFFFu : 0u;
                const uint4 a = *(const uint4*)&Y[ij.x * WPN];
                const uint4 b = *(const uint4*)&Y[ij.y * WPN];
                uint4 r;
                r.x = (a.x & b.x) ^ xm;  r.y = (a.y & b.y) ^ xm;
                r.z = (a.z & b.z) ^ xm;  r.w = (a.w & b.w) ^ xm;
                *(uint4*)&R[n * WPN] = r;
            }

            // (c) unpack 64 rows of previous chunk's result -> global
            if (do_unpack && F <= 15) {
                #pragma unroll
                for (int s = 0; s < 2; ++s) {
                    const int r = F * 64 + s * 32 + wv * 2 + half;
                    const uint4 w4 = *(const uint4*)&R[r * WPN];
                    uint4 v;
                    v.x = (w4.x >> lane32) & 1u;
                    v.y = (w4.y >> lane32) & 1u;
                    v.z = (w4.z >> lane32) & 1u;
                    v.w = (w4.w >> lane32) & 1u;
                    *(uint4*)(out + (size_t)r * W + c0p + lane32 * 4) = v;
                }
            }

            // (d) ballot-commit the pack rows issued at (a)
            if (do_pack && F >= 1) {
                {
                    const unsigned long long b0 = __ballot(pv0.x != 0u);
                    const unsigned long long b1 = __ballot(pv0.y != 0u);
                    const unsigned long long b2 = __ballot(pv0.z != 0u);
                    const unsigned long long b3 = __ballot(pv0.w != 0u);
                    if (lane32 == 0) {
                        uint4 w;
                        w.x = (uint32_t)(b0 >> shift);
                        w.y = (uint32_t)(b1 >> shift);
                        w.z = (uint32_t)(b2 >> shift);
                        w.w = (uint32_t)(b3 >> shift);
                        *(uint4*)&P[pr0 * WPN] = w;
                    }
                }
                {
                    const unsigned long long b0 = __ballot(pv1.x != 0u);
                    const unsigned long long b1 = __ballot(pv1.y != 0u);
                    const unsigned long long b2 = __ballot(pv1.z != 0u);
                    const unsigned long long b3 = __ballot(pv1.w != 0u);
                    if (lane32 == 0) {
                        uint4 w;
                        w.x = (uint32_t)(b0 >> shift);
                        w.y = (uint32_t)(b1 >> shift);
                        w.z = (uint32_t)(b2 >> shift);
                        w.w = (uint32_t)(b3 >> shift);
                        *(uint4*)&P[pr1 * WPN] = w;
                    }
                }
            }

            if (F <= 14) {
                #pragma unroll
                for (int k = 0; k < 4; ++k) tc[k] = tn[k];
            }
            __syncthreads();
        }
    }

    // ---------------- epilogue: unpack last chunk's result ----------------
    {
        const int c0l = bcol + (CPW - 1) * CHUNK;
        #pragma unroll 4
        for (int s = 0; s < 32; ++s) {
            const int r = s * 32 + wv * 2 + half;
            const uint4 w4 = *(const uint4*)&R[r * WPN];
            uint4 v;
            v.x = (w4.x >> lane32) & 1u;
            v.y = (w4.y >> lane32) & 1u;
            v.z = (w4.z >> lane32) & 1u;
            v.w = (w4.w >> lane32) & 1u;
            *(uint4*)(out + (size_t)r * W + c0l + lane32 * 4) = v;
        }
    }
}

// ---------------------------------------------------------------------------
// Fallback (R5 kernel, unfused) if workspace is too small for the tables.
// ---------------------------------------------------------------------------
__global__ __launch_bounds__(THREADS, 4)
void nand_pipe128_kernel(const uint32_t* __restrict__ in,
                         const int*      __restrict__ idx_first,
                         const uint32_t* __restrict__ mask_first,
                         const int*      __restrict__ idx_mid,
                         const uint32_t* __restrict__ mask_mid,
                         const int*      __restrict__ idx_last,
                         const uint32_t* __restrict__ mask_last,
                         uint32_t*       __restrict__ out)
{
    __shared__ uint32_t lds[40960];
    uint32_t* P = lds;
    uint32_t* X = lds + 4096;
    uint32_t* Y = lds + 20480;
    uint32_t* R = lds + 36864;

    const int t      = threadIdx.x;
    const int l      = t & 63;
    const int wv     = t >> 6;
    const int lane32 = l & 31;
    const int half   = l >> 5;
    const int shift  = half ? 32 : 0;
    const int bcol   = blockIdx.x * (CPW * CHUNK);

    #pragma unroll 4
    for (int s = 0; s < 32; ++s) {
        const int r = s * 32 + wv * 2 + half;
        const uint4 v = *(const uint4*)(in + (size_t)r * W + bcol + lane32 * 4);
        const unsigned long long b0 = __ballot(v.x != 0u);
        const unsigned long long b1 = __ballot(v.y != 0u);
        const unsigned long long b2 = __ballot(v.z != 0u);
        const unsigned long long b3 = __ballot(v.w != 0u);
        if (lane32 == 0) {
            uint4 w;
            w.x = (uint32_t)(b0 >> shift);  w.y = (uint32_t)(b1 >> shift);
            w.z = (uint32_t)(b2 >> shift);  w.w = (uint32_t)(b3 >> shift);
            *(uint4*)&P[r * WPN] = w;
        }
    }
    __syncthreads();

    for (int i = 0; i < CPW; ++i) {
        const int c0n = bcol + (i + 1) * CHUNK;
        const int c0p = bcol + (i - 1) * CHUNK;
        const bool do_pack   = (i + 1 < CPW);
        const bool do_unpack = (i > 0);

        for (int L = 0; L <= 32; ++L) {
            uint4 pv = {0, 0, 0, 0};
            int   pr = 0;
            if (do_pack && L >= 1) {
                pr = (L - 1) * 32 + wv * 2 + half;
                pv = *(const uint4*)(in + (size_t)pr * W + c0n + lane32 * 4);
            }
            if (L == 0) {
                #pragma unroll
                for (int k = 0; k < NN / THREADS; ++k) {
                    const int n = k * THREADS + t;
                    const int2 ij = ((const int2*)idx_first)[n];
                    const uint32_t xm = mask_first[n] ? 0xFFFFFFFFu : 0u;
                    const uint4 a = *(const uint4*)&P[ij.x * WPN];
                    const uint4 b = *(const uint4*)&P[ij.y * WPN];
                    uint4 r;
                    r.x = (a.x & b.x) ^ xm;  r.y = (a.y & b.y) ^ xm;
                    r.z = (a.z & b.z) ^ xm;  r.w = (a.w & b.w) ^ xm;
                    *(uint4*)&X[n * WPN] = r;
                }
            } else if (L <= 31) {
                const int*      idxL = idx_mid + (size_t)(L - 1) * NN * 2;
                const uint32_t* mL   = mask_mid + (size_t)(L - 1) * NN;
                const uint32_t* src  = (L & 1) ? X : Y;
                uint32_t*       dst  = (L & 1) ? Y : X;
                #pragma unroll
                for (int k = 0; k < NN / THREADS; ++k) {
                    const int n = k * THREADS + t;
                    const int2 ij = ((const int2*)idxL)[n];
                    const uint32_t xm = mL[n] ? 0xFFFFFFFFu : 0u;
                    const uint4 a = *(const uint4*)&src[ij.x * WPN];
                    const uint4 b = *(const uint4*)&src[ij.y * WPN];
                    uint4 r;
                    r.x = (a.x & b.x) ^ xm;  r.y = (a.y & b.y) ^ xm;
                    r.z = (a.z & b.z) ^ xm;  r.w = (a.w & b.w) ^ xm;
                    *(uint4*)&dst[n * WPN] = r;
                }
            } else {
                const int n = t;
                const int2 ij = ((const int2*)idx_last)[n];
                const uint32_t xm = mask_last[n] ? 0xFFFFFFFFu : 0u;
                const uint4 a = *(const uint4*)&Y[ij.x * WPN];
                const uint4 b = *(const uint4*)&Y[ij.y * WPN];
                uint4 r;
                r.x = (a.x & b.x) ^ xm;  r.y = (a.y & b.y) ^ xm;
                r.z = (a.z & b.z) ^ xm;  r.w = (a.w & b.w) ^ xm;
                *(uint4*)&R[n * WPN] = r;
            }
            if (do_unpack && L <= 31) {
                const int r = L * 32 + wv * 2 + half;
                const uint4 w4 = *(const uint4*)&R[r * WPN];
                uint4 v;
                v.x = (w4.x >> lane32) & 1u;  v.y = (w4.y >> lane32) & 1u;
                v.z = (w4.z >> lane32) & 1u;  v.w = (w4.w >> lane32) & 1u;
                *(uint4*)(out + (size_t)r * W + c0p + lane32 * 4) = v;
            }
            if (do_pack && L >= 1) {
                const unsigned long long b0 = __ballot(pv.x != 0u);
                const unsigned long long b1 = __ballot(pv.y != 0u);
                const unsigned long long b2 = __ballot(pv.z != 0u);
                const unsigned long long b3 = __ballot(pv.w != 0u);
                if (lane32 == 0) {
                    uint4 w;
                    w.x = (uint32_t)(b0 >> shift);  w.y = (uint32_t)(b1 >> shift);
                    w.z = (uint32_t)(b2 >> shift);  w.w = (uint32_t)(b3 >> shift);
                    *(uint4*)&P[pr * WPN] = w;
                }
            }
            __syncthreads();
        }
    }
    {
        const int c0l = bcol + (CPW - 1) * CHUNK;
        #pragma unroll 4
        for (int s = 0; s < 32; ++s) {
            const int r = s * 32 + wv * 2 + half;
            const uint4 w4 = *(const uint4*)&R[r * WPN];
            uint4 v;
            v.x = (w4.x >> lane32) & 1u;  v.y = (w4.y >> lane32) & 1u;
            v.z = (w4.z >> lane32) & 1u;  v.w = (w4.w >> lane32) & 1u;
            *(uint4*)(out + (size_t)r * W + c0l + lane32 * 4) = v;
        }
    }
}

extern "C" void kernel_launch(void* const* d_in, const int* in_sizes, int n_in,
                              void* d_out, int out_size, void* d_ws, size_t ws_size,
                              hipStream_t stream) {
    const uint32_t* in         = (const uint32_t*)d_in[0];
    const int*      idx_first  = (const int*)d_in[1];
    const uint32_t* mask_first = (const uint32_t*)d_in[2];
    const int*      idx_mid    = (const int*)d_in[3];
    const uint32_t* mask_mid   = (const uint32_t*)d_in[4];
    const int*      idx_last   = (const int*)d_in[5];
    const uint32_t* mask_last  = (const uint32_t*)d_in[6];
    uint32_t*       out        = (uint32_t*)d_out;

    if (ws_size >= TBL_BYTES) {
        uint4* tbl = (uint4*)d_ws;
        build_sorted_tbl_kernel<<<NPAIRS, 1024, 0, stream>>>(
            idx_first, mask_first, idx_mid, mask_mid, tbl);
        nand_fused_kernel<<<GRID, THREADS, 0, stream>>>(
            in, tbl, idx_last, mask_last, out);
    } else {
        nand_pipe128_kernel<<<GRID, THREADS, 0, stream>>>(
            in, idx_first, mask_first, idx_mid, mask_mid, idx_last, mask_last, out);
    }
}

// Round 8
// 151.894 us; speedup vs baseline: 1.2075x; 1.2075x over previous
//
#include <hip/hip_runtime.h>
#include <stdint.h>

#define NINPUTS   1024
#define NOUTPUTS  1024
#define NMID      31          // middle layers
#define NN        4096        // neurons per layer
#define W         65536       // bit-array width
#define CHUNK     128         // columns per chunk (512-B rows: min clean HBM granule)
#define WPN       4           // u32 words per row (CHUNK/32)
#define NCHUNKS   (W / CHUNK) // 512
#define GRID      256         // 1 WG per CU
#define CPW       (NCHUNKS / GRID)   // 2 chunks per WG, pipelined
#define THREADS   1024
#define NPAIRS    16          // fused layer-pairs (L0,L1)..(L30,L31); L32 single
#define TBL_BYTES ((size_t)NPAIRS * NN * 16)

// ---------------------------------------------------------------------------
// Prep kernel (R6 version, IDENTITY order — R7's class-sorted order regressed:
// conflicts 1.77e7 -> 2.45e7 because scattered writes lost their conflict-free
// contiguity and read balancing was only approximate).
// Pair F computes layer 2F+1 from layer 2F's input state:
//   r = (((s[a1]&s[b1])^m1) & ((s[a2]&s[b2])^m2)) ^ m3
// Entry (uint4 e): e.x = a1*16 | m1<<31; e.y = b1*16;
//                  e.z = a2*16 | m2<<31; e.w = b2*16 | m3<<31.
// ---------------------------------------------------------------------------
__global__ void build_tbl_kernel(const int*      __restrict__ idx_first,
                                 const uint32_t* __restrict__ mask_first,
                                 const int*      __restrict__ idx_mid,
                                 const uint32_t* __restrict__ mask_mid,
                                 uint4*          __restrict__ tbl)
{
    const int tid = blockIdx.x * blockDim.x + threadIdx.x;   // 0..65535
    const int F = tid >> 12;
    const int n = tid & (NN - 1);

    const int*      i1;
    const uint32_t* m1;
    if (F == 0) { i1 = idx_first; m1 = mask_first; }
    else        { i1 = idx_mid + (size_t)(2 * F - 1) * NN * 2;
                  m1 = mask_mid + (size_t)(2 * F - 1) * NN; }
    const int*      i2 = idx_mid + (size_t)(2 * F) * NN * 2;
    const uint32_t* m2 = mask_mid + (size_t)(2 * F) * NN;

    const int j = i2[2 * n];
    const int k = i2[2 * n + 1];
    uint4 e;
    e.x = (uint32_t)(i1[2 * j]     * 16) | (m1[j] ? 0x80000000u : 0u);
    e.y = (uint32_t)(i1[2 * j + 1] * 16);
    e.z = (uint32_t)(i1[2 * k]     * 16) | (m1[k] ? 0x80000000u : 0u);
    e.w = (uint32_t)(i1[2 * k + 1] * 16) | (m2[n] ? 0x80000000u : 0u);
    tbl[(size_t)F * NN + n] = e;
}

// ---------------------------------------------------------------------------
// Main kernel: R6 structure (17 rounds/chunk, pipelined pack/unpack, register
// table prefetch) with BATCHED gather reads: all 16 ds_read_b128 issued
// before any compute (R6's VGPR_Count=52 showed the compiler serialized into
// 4 dependent chains ~600cyc; batching gives 16 outstanding reads/wave).
// LDS 160 KiB: P (16K) | X (64K) | Y (64K) | R (16K).
// ---------------------------------------------------------------------------
__global__ __launch_bounds__(THREADS, 4)
void nand_fused_kernel(const uint32_t* __restrict__ in,         // [1024][W]
                       const uint4*    __restrict__ tbl,        // [16][NN]
                       const int*      __restrict__ idx_last,   // [NOUTPUTS][2]
                       const uint32_t* __restrict__ mask_last,  // [NOUTPUTS]
                       uint32_t*       __restrict__ out)        // [NOUTPUTS][W]
{
    __shared__ uint32_t lds[40960];          // 160 KiB exactly
    uint32_t* P = lds;                       // 1024 * 4 dwords (16 KB)
    uint32_t* X = lds + 4096;                // 4096 * 4 dwords (64 KB)
    uint32_t* Y = lds + 20480;               // 4096 * 4 dwords (64 KB)
    uint32_t* R = lds + 36864;               // 1024 * 4 dwords (16 KB)

    const int t      = threadIdx.x;
    const int l      = t & 63;
    const int wv     = t >> 6;               // wave 0..15
    const int lane32 = l & 31;
    const int half   = l >> 5;
    const int shift  = half ? 32 : 0;
    const int bcol   = blockIdx.x * (CPW * CHUNK);

    // ---------------- prologue: pack chunk 0 fully into P ----------------
    #pragma unroll 4
    for (int s = 0; s < 32; ++s) {
        const int r = s * 32 + wv * 2 + half;
        const uint4 v = *(const uint4*)(in + (size_t)r * W + bcol + lane32 * 4);
        const unsigned long long b0 = __ballot(v.x != 0u);
        const unsigned long long b1 = __ballot(v.y != 0u);
        const unsigned long long b2 = __ballot(v.z != 0u);
        const unsigned long long b3 = __ballot(v.w != 0u);
        if (lane32 == 0) {
            uint4 w;
            w.x = (uint32_t)(b0 >> shift);
            w.y = (uint32_t)(b1 >> shift);
            w.z = (uint32_t)(b2 >> shift);
            w.w = (uint32_t)(b3 >> shift);
            *(uint4*)&P[r * WPN] = w;
        }
    }
    __syncthreads();

    for (int i = 0; i < CPW; ++i) {
        const int c0n = bcol + (i + 1) * CHUNK;      // pack source cols
        const int c0p = bcol + (i - 1) * CHUNK;      // unpack dest cols
        const bool do_pack   = (i + 1 < CPW);
        const bool do_unpack = (i > 0);

        // cold-load round-0 table entries for this chunk
        uint4 tc[4], tn[4];
        #pragma unroll
        for (int k = 0; k < 4; ++k) tc[k] = tbl[k * THREADS + t];

        for (int F = 0; F <= 16; ++F) {
            // (a) issue next-chunk input loads (2 rows/thread -> 64 rows/WG)
            uint4 pv0 = {0,0,0,0}, pv1 = {0,0,0,0};
            int pr0 = 0, pr1 = 0;
            if (do_pack && F >= 1) {
                pr0 = (F - 1) * 64 + wv * 2 + half;
                pr1 = pr0 + 32;
                pv0 = *(const uint4*)(in + (size_t)pr0 * W + c0n + lane32 * 4);
                pv1 = *(const uint4*)(in + (size_t)pr1 * W + c0n + lane32 * 4);
            }

            // (b) fused gather-NAND: issue ALL 16 reads, then compute+write
            if (F <= 15) {
                const uint32_t* src = (F == 0) ? P : ((F & 1) ? X : Y);
                uint32_t*       dst = (F & 1) ? Y : X;
                uint4 A[4], B[4], C[4], D[4];
                #pragma unroll
                for (int k = 0; k < 4; ++k) {
                    const uint4 e = tc[k];
                    A[k] = *(const uint4*)((const char*)src + (e.x & 0xFFFFu));
                    B[k] = *(const uint4*)((const char*)src + e.y);
                    C[k] = *(const uint4*)((const char*)src + (e.z & 0xFFFFu));
                    D[k] = *(const uint4*)((const char*)src + (e.w & 0xFFFFu));
                }
                #pragma unroll
                for (int k = 0; k < 4; ++k) {
                    const int n = k * THREADS + t;
                    const uint4 e = tc[k];
                    const uint32_t xm1 = (uint32_t)((int32_t)e.x >> 31);
                    const uint32_t xm2 = (uint32_t)((int32_t)e.z >> 31);
                    const uint32_t xm3 = (uint32_t)((int32_t)e.w >> 31);
                    uint4 r;
                    r.x = (((A[k].x & B[k].x) ^ xm1) & ((C[k].x & D[k].x) ^ xm2)) ^ xm3;
                    r.y = (((A[k].y & B[k].y) ^ xm1) & ((C[k].y & D[k].y) ^ xm2)) ^ xm3;
                    r.z = (((A[k].z & B[k].z) ^ xm1) & ((C[k].z & D[k].z) ^ xm2)) ^ xm3;
                    r.w = (((A[k].w & B[k].w) ^ xm1) & ((C[k].w & D[k].w) ^ xm2)) ^ xm3;
                    *(uint4*)&dst[n * WPN] = r;
                }
            } else {                                 // F == 16: last layer Y -> R
                const int n = t;
                const int2 ij = ((const int2*)idx_last)[n];
                const uint32_t xm = mask_last[n] ? 0xFFFFFFFFu : 0u;
                const uint4 a = *(const uint4*)&Y[ij.x * WPN];
                const uint4 b = *(const uint4*)&Y[ij.y * WPN];
                uint4 r;
                r.x = (a.x & b.x) ^ xm;  r.y = (a.y & b.y) ^ xm;
                r.z = (a.z & b.z) ^ xm;  r.w = (a.w & b.w) ^ xm;
                *(uint4*)&R[n * WPN] = r;
            }

            // (a') prefetch next round's table entries (L2-hot, 1 MB table)
            if (F <= 14) {
                #pragma unroll
                for (int k = 0; k < 4; ++k)
                    tn[k] = tbl[(size_t)(F + 1) * NN + k * THREADS + t];
            }

            // (c) unpack 64 rows of previous chunk's result -> global
            if (do_unpack && F <= 15) {
                #pragma unroll
                for (int s = 0; s < 2; ++s) {
                    const int r = F * 64 + s * 32 + wv * 2 + half;
                    const uint4 w4 = *(const uint4*)&R[r * WPN];
                    uint4 v;
                    v.x = (w4.x >> lane32) & 1u;
                    v.y = (w4.y >> lane32) & 1u;
                    v.z = (w4.z >> lane32) & 1u;
                    v.w = (w4.w >> lane32) & 1u;
                    *(uint4*)(out + (size_t)r * W + c0p + lane32 * 4) = v;
                }
            }

            // (d) ballot-commit the pack rows issued at (a)
            if (do_pack && F >= 1) {
                {
                    const unsigned long long b0 = __ballot(pv0.x != 0u);
                    const unsigned long long b1 = __ballot(pv0.y != 0u);
                    const unsigned long long b2 = __ballot(pv0.z != 0u);
                    const unsigned long long b3 = __ballot(pv0.w != 0u);
                    if (lane32 == 0) {
                        uint4 w;
                        w.x = (uint32_t)(b0 >> shift);
                        w.y = (uint32_t)(b1 >> shift);
                        w.z = (uint32_t)(b2 >> shift);
                        w.w = (uint32_t)(b3 >> shift);
                        *(uint4*)&P[pr0 * WPN] = w;
                    }
                }
                {
                    const unsigned long long b0 = __ballot(pv1.x != 0u);
                    const unsigned long long b1 = __ballot(pv1.y != 0u);
                    const unsigned long long b2 = __ballot(pv1.z != 0u);
                    const unsigned long long b3 = __ballot(pv1.w != 0u);
                    if (lane32 == 0) {
                        uint4 w;
                        w.x = (uint32_t)(b0 >> shift);
                        w.y = (uint32_t)(b1 >> shift);
                        w.z = (uint32_t)(b2 >> shift);
                        w.w = (uint32_t)(b3 >> shift);
                        *(uint4*)&P[pr1 * WPN] = w;
                    }
                }
            }

            if (F <= 14) {
                #pragma unroll
                for (int k = 0; k < 4; ++k) tc[k] = tn[k];
            }
            __syncthreads();
        }
    }

    // ---------------- epilogue: unpack last chunk's result ----------------
    {
        const int c0l = bcol + (CPW - 1) * CHUNK;
        #pragma unroll 4
        for (int s = 0; s < 32; ++s) {
            const int r = s * 32 + wv * 2 + half;
            const uint4 w4 = *(const uint4*)&R[r * WPN];
            uint4 v;
            v.x = (w4.x >> lane32) & 1u;
            v.y = (w4.y >> lane32) & 1u;
            v.z = (w4.z >> lane32) & 1u;
            v.w = (w4.w >> lane32) & 1u;
            *(uint4*)(out + (size_t)r * W + c0l + lane32 * 4) = v;
        }
    }
}

// ---------------------------------------------------------------------------
// Fallback (R5 kernel, unfused) if workspace is too small for the tables.
// ---------------------------------------------------------------------------
__global__ __launch_bounds__(THREADS, 4)
void nand_pipe128_kernel(const uint32_t* __restrict__ in,
                         const int*      __restrict__ idx_first,
                         const uint32_t* __restrict__ mask_first,
                         const int*      __restrict__ idx_mid,
                         const uint32_t* __restrict__ mask_mid,
                         const int*      __restrict__ idx_last,
                         const uint32_t* __restrict__ mask_last,
                         uint32_t*       __restrict__ out)
{
    __shared__ uint32_t lds[40960];
    uint32_t* P = lds;
    uint32_t* X = lds + 4096;
    uint32_t* Y = lds + 20480;
    uint32_t* R = lds + 36864;

    const int t      = threadIdx.x;
    const int l      = t & 63;
    const int wv     = t >> 6;
    const int lane32 = l & 31;
    const int half   = l >> 5;
    const int shift  = half ? 32 : 0;
    const int bcol   = blockIdx.x * (CPW * CHUNK);

    #pragma unroll 4
    for (int s = 0; s < 32; ++s) {
        const int r = s * 32 + wv * 2 + half;
        const uint4 v = *(const uint4*)(in + (size_t)r * W + bcol + lane32 * 4);
        const unsigned long long b0 = __ballot(v.x != 0u);
        const unsigned long long b1 = __ballot(v.y != 0u);
        const unsigned long long b2 = __ballot(v.z != 0u);
        const unsigned long long b3 = __ballot(v.w != 0u);
        if (lane32 == 0) {
            uint4 w;
            w.x = (uint32_t)(b0 >> shift);  w.y = (uint32_t)(b1 >> shift);
            w.z = (uint32_t)(b2 >> shift);  w.w = (uint32_t)(b3 >> shift);
            *(uint4*)&P[r * WPN] = w;
        }
    }
    __syncthreads();

    for (int i = 0; i < CPW; ++i) {
        const int c0n = bcol + (i + 1) * CHUNK;
        const int c0p = bcol + (i - 1) * CHUNK;
        const bool do_pack   = (i + 1 < CPW);
        const bool do_unpack = (i > 0);

        for (int L = 0; L <= 32; ++L) {
            uint4 pv = {0, 0, 0, 0};
            int   pr = 0;
            if (do_pack && L >= 1) {
                pr = (L - 1) * 32 + wv * 2 + half;
                pv = *(const uint4*)(in + (size_t)pr * W + c0n + lane32 * 4);
            }
            if (L == 0) {
                #pragma unroll
                for (int k = 0; k < NN / THREADS; ++k) {
                    const int n = k * THREADS + t;
                    const int2 ij = ((const int2*)idx_first)[n];
                    const uint32_t xm = mask_first[n] ? 0xFFFFFFFFu : 0u;
                    const uint4 a = *(const uint4*)&P[ij.x * WPN];
                    const uint4 b = *(const uint4*)&P[ij.y * WPN];
                    uint4 r;
                    r.x = (a.x & b.x) ^ xm;  r.y = (a.y & b.y) ^ xm;
                    r.z = (a.z & b.z) ^ xm;  r.w = (a.w & b.w) ^ xm;
                    *(uint4*)&X[n * WPN] = r;
                }
            } else if (L <= 31) {
                const int*      idxL = idx_mid + (size_t)(L - 1) * NN * 2;
                const uint32_t* mL   = mask_mid + (size_t)(L - 1) * NN;
                const uint32_t* src  = (L & 1) ? X : Y;
                uint32_t*       dst  = (L & 1) ? Y : X;
                #pragma unroll
                for (int k = 0; k < NN / THREADS; ++k) {
                    const int n = k * THREADS + t;
                    const int2 ij = ((const int2*)idxL)[n];
                    const uint32_t xm = mL[n] ? 0xFFFFFFFFu : 0u;
                    const uint4 a = *(const uint4*)&src[ij.x * WPN];
                    const uint4 b = *(const uint4*)&src[ij.y * WPN];
                    uint4 r;
                    r.x = (a.x & b.x) ^ xm;  r.y = (a.y & b.y) ^ xm;
                    r.z = (a.z & b.z) ^ xm;  r.w = (a.w & b.w) ^ xm;
                    *(uint4*)&dst[n * WPN] = r;
                }
            } else {
                const int n = t;
                const int2 ij = ((const int2*)idx_last)[n];
                const uint32_t xm = mask_last[n] ? 0xFFFFFFFFu : 0u;
                const uint4 a = *(const uint4*)&Y[ij.x * WPN];
                const uint4 b = *(const uint4*)&Y[ij.y * WPN];
                uint4 r;
                r.x = (a.x & b.x) ^ xm;  r.y = (a.y & b.y) ^ xm;
                r.z = (a.z & b.z) ^ xm;  r.w = (a.w & b.w) ^ xm;
                *(uint4*)&R[n * WPN] = r;
            }
            if (do_unpack && L <= 31) {
                const int r = L * 32 + wv * 2 + half;
                const uint4 w4 = *(const uint4*)&R[r * WPN];
                uint4 v;
                v.x = (w4.x >> lane32) & 1u;  v.y = (w4.y >> lane32) & 1u;
                v.z = (w4.z >> lane32) & 1u;  v.w = (w4.w >> lane32) & 1u;
                *(uint4*)(out + (size_t)r * W + c0p + lane32 * 4) = v;
            }
            if (do_pack && L >= 1) {
                const unsigned long long b0 = __ballot(pv.x != 0u);
                const unsigned long long b1 = __ballot(pv.y != 0u);
                const unsigned long long b2 = __ballot(pv.z != 0u);
                const unsigned long long b3 = __ballot(pv.w != 0u);
                if (lane32 == 0) {
                    uint4 w;
                    w.x = (uint32_t)(b0 >> shift);  w.y = (uint32_t)(b1 >> shift);
                    w.z = (uint32_t)(b2 >> shift);  w.w = (uint32_t)(b3 >> shift);
                    *(uint4*)&P[pr * WPN] = w;
                }
            }
            __syncthreads();
        }
    }
    {
        const int c0l = bcol + (CPW - 1) * CHUNK;
        #pragma unroll 4
        for (int s = 0; s < 32; ++s) {
            const int r = s * 32 + wv * 2 + half;
            const uint4 w4 = *(const uint4*)&R[r * WPN];
            uint4 v;
            v.x = (w4.x >> lane32) & 1u;  v.y = (w4.y >> lane32) & 1u;
            v.z = (w4.z >> lane32) & 1u;  v.w = (w4.w >> lane32) & 1u;
            *(uint4*)(out + (size_t)r * W + c0l + lane32 * 4) = v;
        }
    }
}

extern "C" void kernel_launch(void* const* d_in, const int* in_sizes, int n_in,
                              void* d_out, int out_size, void* d_ws, size_t ws_size,
                              hipStream_t stream) {
    const uint32_t* in         = (const uint32_t*)d_in[0];
    const int*      idx_first  = (const int*)d_in[1];
    const uint32_t* mask_first = (const uint32_t*)d_in[2];
    const int*      idx_mid    = (const int*)d_in[3];
    const uint32_t* mask_mid   = (const uint32_t*)d_in[4];
    const int*      idx_last   = (const int*)d_in[5];
    const uint32_t* mask_last  = (const uint32_t*)d_in[6];
    uint32_t*       out        = (uint32_t*)d_out;

    if (ws_size >= TBL_BYTES) {
        uint4* tbl = (uint4*)d_ws;
        build_tbl_kernel<<<(NPAIRS * NN) / 256, 256, 0, stream>>>(
            idx_first, mask_first, idx_mid, mask_mid, tbl);
        nand_fused_kernel<<<GRID, THREADS, 0, stream>>>(
            in, tbl, idx_last, mask_last, out);
    } else {
        nand_pipe128_kernel<<<GRID, THREADS, 0, stream>>>(
            in, idx_first, mask_first, idx_mid, mask_mid, idx_last, mask_last, out);
    }
}